// Round 4
// baseline (468.198 us; speedup 1.0000x reference)
//
#include <hip/hip_runtime.h>
#include <stdint.h>

#define H 256
#define NATOMS 100000
#define MB 16

typedef float floatx4 __attribute__((ext_vector_type(4)));
typedef short short8 __attribute__((ext_vector_type(8)));
typedef short short4v __attribute__((ext_vector_type(4)));

__device__ __forceinline__ unsigned short f2bf(float x) {
    union { float f; uint32_t u; } c; c.f = x;
    return (unsigned short)((c.u + 0x7FFFu + ((c.u >> 16) & 1u)) >> 16);
}

// ---------------------------------------------------------------------------
// Pack weights (f32 [K][N] row-major) into bf16 MFMA-B-fragment order:
// frag (kb, nb): P[(fragBase + fl)*512 + l*8 + e] = W[kb*32 + (l>>4)*8 + e][nb*16 + (l&15)]
// fl = nb*(K/32) + kb.
// Layout in ws (bf16 elems): U@0, V@65536, W1@131072, W2@262144.
// ---------------------------------------------------------------------------
__global__ void pack_weights(const float* __restrict__ U_W, const float* __restrict__ V_W,
                             const float* __restrict__ W1, const float* __restrict__ W2,
                             unsigned short* __restrict__ P) {
    int gtid = blockIdx.x * 256 + threadIdx.x;
    int fid = gtid >> 6, l = gtid & 63;
    const float* src; int K, N, fl; unsigned short* dst;
    if (fid < 128)      { src = U_W; K = 256; N = 256; fl = fid;       dst = P; }
    else if (fid < 256) { src = V_W; K = 256; N = 256; fl = fid - 128; dst = P + 65536; }
    else if (fid < 512) { src = W1;  K = 512; N = 256; fl = fid - 256; dst = P + 131072; }
    else                { src = W2;  K = 256; N = 768; fl = fid - 512; dst = P + 262144; }
    int kbc = K >> 5;
    int nb = fl / kbc, kb = fl - nb * kbc;
    int k0 = kb * 32 + ((l >> 4) << 3);
    int n0 = nb * 16 + (l & 15);
    short8 outv;
#pragma unroll
    for (int e = 0; e < 8; e++) outv[e] = (short)f2bf(src[(size_t)(k0 + e) * N + n0]);
    *(short8*)(dst + (size_t)fl * 512 + l * 8) = outv;
}

// ---------------------------------------------------------------------------
// Fused PaiNN mixing: one block = 16 atoms, 512 threads (8 waves), 2 blocks/CU.
// Everything in LDS is stored MFMA-A-fragment-linear: frag f at byte f*1024,
// lane l's 16B at f*1024 + l*16.  Element (row a, k): frag covers k-range
// [ks*32,ks*32+32), slot = (a&15) | (((k>>3)&3)<<4), byte e = (k&7)*2.
// A_buf: frags (d*8+ks) of v-tile (24KB); frags 0..7 reused for hid after p1.
// ctxin: frags 0..7 = s_normed (k 0..255), frags 8..15 = Vv_norm (k 256..511).
// Wave w owns output cols [32w, 32w+32) in every GEMM (cf in {0,1}).
// ---------------------------------------------------------------------------
__global__ __launch_bounds__(512, 4) void painn_main(
    const float* __restrict__ s, const float* __restrict__ v,
    const float* __restrict__ gamma, const float* __restrict__ beta,
    const float* __restrict__ b1, const float* __restrict__ b2,
    const unsigned short* __restrict__ P,
    float* __restrict__ s_out, float* __restrict__ v_out) {

    __shared__ unsigned short A_buf[12288];   // 24KB
    __shared__ unsigned short ctxin[8192];    // 16KB

    const int tid = threadIdx.x;
    const int w = tid >> 6, l = tid & 63;
    const int l15 = l & 15, lhi = l >> 4;
    const int atom0 = blockIdx.x * MB;

    // ---- phase 0a: stage v tile -> LDS bf16 in fragment-linear order ----
    // idx -> (a = idx&15, r = idx>>4, d = r>>6, c4 = r&63): global reads are
    // 16 full 64B lines per instr; LDS writes conflict-free (bank = f(a)).
    {
#pragma unroll
        for (int i = 0; i < 6; i++) {
            int idx = i * 512 + tid;
            int a = idx & 15, r = idx >> 4;
            int d = r >> 6, c4 = r & 63;
            floatx4 val = *(const floatx4*)(v + ((size_t)(atom0 + a) * 3 + d) * H + c4 * 4);
            short4v pk;
#pragma unroll
            for (int j = 0; j < 4; j++) pk[j] = (short)f2bf(val[j]);
            int ks = c4 >> 3, kpos = (c4 >> 1) & 3;
            int bo = (d * 8 + ks) * 1024 + a * 16 + kpos * 256 + (c4 & 1) * 8;
            *(short4v*)((char*)A_buf + bo) = pk;
        }
    }

    // ---- phase 0b: LayerNorm(s) -> ctxin frags 0..7 ----
    {
        int a = tid >> 5, lg = tid & 31;      // 32 lanes per atom
        const floatx4* srow = (const floatx4*)(s + (size_t)(atom0 + a) * H);
        floatx4 vals[2];
        float sum = 0.f, sumsq = 0.f;
#pragma unroll
        for (int i = 0; i < 2; i++) {
            vals[i] = srow[lg + (i << 5)];
#pragma unroll
            for (int j = 0; j < 4; j++) { sum += vals[i][j]; sumsq += vals[i][j] * vals[i][j]; }
        }
#pragma unroll
        for (int m = 1; m < 32; m <<= 1) { sum += __shfl_xor(sum, m); sumsq += __shfl_xor(sumsq, m); }
        float mu = sum * (1.f / 256.f);
        float var = sumsq * (1.f / 256.f) - mu * mu;
        float rs = rsqrtf(var + 1e-5f);
#pragma unroll
        for (int i = 0; i < 2; i++) {
            int chunk = lg + (i << 5);
            floatx4 g4 = *(const floatx4*)(gamma + chunk * 4);
            floatx4 be4 = *(const floatx4*)(beta + chunk * 4);
            short4v pk;
#pragma unroll
            for (int j = 0; j < 4; j++) pk[j] = (short)f2bf((vals[i][j] - mu) * rs * g4[j] + be4[j]);
            int ks2 = (lg >> 3) + 4 * i;
            int kpos = (lg >> 1) & 3;
            int bo = ks2 * 1024 + a * 16 + kpos * 256 + (lg & 1) * 8;
            *(short4v*)((char*)ctxin + bo) = pk;
        }
    }

    __syncthreads();   // B1

    // ---- phase 1: GEMM Uv & Vv.  A: LDS frags; B: packed global (L2), ping-pong. ----
    floatx4 accU[3][2], accV[3][2];   // [d][cf]
#pragma unroll
    for (int d = 0; d < 3; d++)
#pragma unroll
        for (int cf = 0; cf < 2; cf++) { accU[d][cf] = (floatx4)0.f; accV[d][cf] = (floatx4)0.f; }

    {
        const short8* PU = (const short8*)(P);
        const short8* PV = (const short8*)(P + 65536);
        short8 bU[2][2], bV[2][2];
#pragma unroll
        for (int cf = 0; cf < 2; cf++) {
            int fl = (2 * w + cf) * 8;
            bU[0][cf] = PU[(size_t)fl * 64 + l];
            bV[0][cf] = PV[(size_t)fl * 64 + l];
        }
#pragma unroll
        for (int ks = 0; ks < 8; ks++) {
            int cur = ks & 1, nxt = cur ^ 1;
            if (ks < 7) {
#pragma unroll
                for (int cf = 0; cf < 2; cf++) {
                    int fl = (2 * w + cf) * 8 + ks + 1;
                    bU[nxt][cf] = PU[(size_t)fl * 64 + l];
                    bV[nxt][cf] = PV[(size_t)fl * 64 + l];
                }
            }
            short8 afr[3];
#pragma unroll
            for (int d = 0; d < 3; d++)
                afr[d] = *(const short8*)((const char*)A_buf + (d * 8 + ks) * 1024 + l * 16);
            __builtin_amdgcn_s_setprio(1);
#pragma unroll
            for (int d = 0; d < 3; d++)
#pragma unroll
                for (int cf = 0; cf < 2; cf++) {
                    accU[d][cf] = __builtin_amdgcn_mfma_f32_16x16x32_bf16(afr[d], bU[cur][cf], accU[d][cf], 0, 0, 0);
                    accV[d][cf] = __builtin_amdgcn_mfma_f32_16x16x32_bf16(afr[d], bV[cur][cf], accV[d][cf], 0, 0, 0);
                }
            __builtin_amdgcn_s_setprio(0);
        }
    }

    // ---- dot_uv (regs) and ||Vv|| -> ctxin frags 8..15 (k = 256+c) ----
    float dotv[2][4];
#pragma unroll
    for (int cf = 0; cf < 2; cf++)
#pragma unroll
        for (int j = 0; j < 4; j++) {
            float du = accU[0][cf][j] * accV[0][cf][j] + accU[1][cf][j] * accV[1][cf][j]
                     + accU[2][cf][j] * accV[2][cf][j];
            dotv[cf][j] = du;
            float nv = sqrtf(accV[0][cf][j] * accV[0][cf][j] + accV[1][cf][j] * accV[1][cf][j]
                           + accV[2][cf][j] * accV[2][cf][j] + 1e-8f);
            int a = (lhi << 2) + j;
            int kpos = (2 * cf + (l15 >> 3)) & 3;
            int bo = (8 + w) * 1024 + (a + kpos * 16) * 16 + (l15 & 7) * 2;
            *(unsigned short*)((char*)ctxin + bo) = f2bf(nv);
        }

    __syncthreads();   // B2

    // ---- phase 2: hidden = silu(ctx_in @ W1 + b1), M=16, K=512 -> hid (A_buf frags 0..7) ----
    {
        floatx4 acc2[2];
#pragma unroll
        for (int cf = 0; cf < 2; cf++) acc2[cf] = (floatx4)0.f;
        const short8* PW1 = (const short8*)(P + 131072);
        short8 bw[2][2];
#pragma unroll
        for (int cf = 0; cf < 2; cf++)
            bw[0][cf] = PW1[(size_t)((2 * w + cf) * 16) * 64 + l];
#pragma unroll
        for (int ks2 = 0; ks2 < 16; ks2++) {
            int cur = ks2 & 1, nxt = cur ^ 1;
            if (ks2 < 15) {
#pragma unroll
                for (int cf = 0; cf < 2; cf++)
                    bw[nxt][cf] = PW1[(size_t)((2 * w + cf) * 16 + ks2 + 1) * 64 + l];
            }
            short8 af = *(const short8*)((const char*)ctxin + ks2 * 1024 + l * 16);
            __builtin_amdgcn_s_setprio(1);
#pragma unroll
            for (int cf = 0; cf < 2; cf++)
                acc2[cf] = __builtin_amdgcn_mfma_f32_16x16x32_bf16(af, bw[cur][cf], acc2[cf], 0, 0, 0);
            __builtin_amdgcn_s_setprio(0);
        }
#pragma unroll
        for (int cf = 0; cf < 2; cf++) {
            int c = (w << 5) + (cf << 4) + l15;
            float bb = b1[c];
            int kpos = (2 * cf + (l15 >> 3)) & 3;
#pragma unroll
            for (int j = 0; j < 4; j++) {
                int a = (lhi << 2) + j;
                float x = acc2[cf][j] + bb;
                float hh = x / (1.f + expf(-x));
                int bo = w * 1024 + (a + kpos * 16) * 16 + (l15 & 7) * 2;
                *(unsigned short*)((char*)A_buf + bo) = f2bf(hh);
            }
        }
    }

    __syncthreads();   // B3

    // ---- phase 3: ctx = hidden @ W2 + b2, K=256, N=768; matched 32-col strips per seg ----
    floatx4 acc3[3][2];   // [seg][cf]
#pragma unroll
    for (int sg = 0; sg < 3; sg++)
#pragma unroll
        for (int cf = 0; cf < 2; cf++) acc3[sg][cf] = (floatx4)0.f;
    {
        const short8* PW2 = (const short8*)(P + 262144);
        short8 bw[2][6];
#pragma unroll
        for (int sg = 0; sg < 3; sg++)
#pragma unroll
            for (int cf = 0; cf < 2; cf++)
                bw[0][sg * 2 + cf] = PW2[(size_t)((sg * 16 + 2 * w + cf) * 8) * 64 + l];
#pragma unroll
        for (int ks3 = 0; ks3 < 8; ks3++) {
            int cur = ks3 & 1, nxt = cur ^ 1;
            if (ks3 < 7) {
#pragma unroll
                for (int sg = 0; sg < 3; sg++)
#pragma unroll
                    for (int cf = 0; cf < 2; cf++)
                        bw[nxt][sg * 2 + cf] = PW2[(size_t)((sg * 16 + 2 * w + cf) * 8 + ks3 + 1) * 64 + l];
            }
            short8 af = *(const short8*)((const char*)A_buf + ks3 * 1024 + l * 16);
            __builtin_amdgcn_s_setprio(1);
#pragma unroll
            for (int sg = 0; sg < 3; sg++)
#pragma unroll
                for (int cf = 0; cf < 2; cf++)
                    acc3[sg][cf] = __builtin_amdgcn_mfma_f32_16x16x32_bf16(af, bw[cur][sg * 2 + cf], acc3[sg][cf], 0, 0, 0);
            __builtin_amdgcn_s_setprio(0);
        }
    }

    // ---- epilogue: registers + L2-warm global re-reads of s, v ----
#pragma unroll
    for (int cf = 0; cf < 2; cf++) {
        int c = (w << 5) + (cf << 4) + l15;
        float bss = b2[c], bsv = b2[256 + c], bvv = b2[512 + c];
#pragma unroll
        for (int j = 0; j < 4; j++) {
            int a = (lhi << 2) + j;
            size_t grow = (size_t)(atom0 + a);
            float a_ss = acc3[0][cf][j] + bss;
            float a_sv = acc3[1][cf][j] + bsv;
            float a_vv = acc3[2][cf][j] + bvv;
            size_t gi = grow * H + c;
            s_out[gi] = s[gi] + a_ss + a_sv * dotv[cf][j];
#pragma unroll
            for (int d = 0; d < 3; d++) {
                size_t vi = (grow * 3 + d) * (size_t)H + c;
                v_out[vi] = v[vi] + a_vv * accU[d][cf][j];
            }
        }
    }
}

extern "C" void kernel_launch(void* const* d_in, const int* in_sizes, int n_in,
                              void* d_out, int out_size, void* d_ws, size_t ws_size,
                              hipStream_t stream) {
    const float* s     = (const float*)d_in[0];
    const float* v     = (const float*)d_in[1];
    const float* gamma = (const float*)d_in[2];
    const float* beta  = (const float*)d_in[3];
    const float* U_W   = (const float*)d_in[4];
    const float* V_W   = (const float*)d_in[5];
    const float* W1    = (const float*)d_in[6];
    const float* b1    = (const float*)d_in[7];
    const float* W2    = (const float*)d_in[8];
    const float* b2    = (const float*)d_in[9];
    float* s_out = (float*)d_out;
    float* v_out = s_out + (size_t)NATOMS * H;
    unsigned short* P = (unsigned short*)d_ws;   // needs 917504 B

    pack_weights<<<dim3(224), dim3(256), 0, stream>>>(U_W, V_W, W1, W2, P);
    painn_main<<<dim3(NATOMS / MB), dim3(512), 0, stream>>>(s, v, gamma, beta, b1, b2, P, s_out, v_out);
}